// Round 3
// baseline (1480.480 us; speedup 1.0000x reference)
//
#include <hip/hip_runtime.h>

#define H_ 8
#define B_ 8
#define S_ 2048
#define D_ 256

// padded LDS strides (halves): kill 8/16-way bank conflicts, keep 16B alignment
#define KSTRIDE 264   // k-tile rows: 528B = 4 banks offset/row
#define VSTRIDE 40    // 32-col tiles: 80B = 20 banks offset/row

typedef __attribute__((ext_vector_type(8))) _Float16 half8;
typedef __attribute__((ext_vector_type(4))) _Float16 half4v;
typedef __attribute__((ext_vector_type(2))) _Float16 half2v;
typedef __attribute__((ext_vector_type(4))) float f32x4;
typedef __attribute__((ext_vector_type(16))) float f32x16;

// split 8 consecutive fp32 into fp16 hi + lo residual
__device__ inline void split8(const float* __restrict__ p, half8& hv, half8& lv) {
  float4 a = *(const float4*)p, b = *(const float4*)(p + 4);
  hv[0] = (_Float16)a.x; hv[1] = (_Float16)a.y; hv[2] = (_Float16)a.z; hv[3] = (_Float16)a.w;
  hv[4] = (_Float16)b.x; hv[5] = (_Float16)b.y; hv[6] = (_Float16)b.z; hv[7] = (_Float16)b.w;
  lv[0] = (_Float16)(a.x - (float)hv[0]); lv[1] = (_Float16)(a.y - (float)hv[1]);
  lv[2] = (_Float16)(a.z - (float)hv[2]); lv[3] = (_Float16)(a.w - (float)hv[3]);
  lv[4] = (_Float16)(b.x - (float)hv[4]); lv[5] = (_Float16)(b.y - (float)hv[5]);
  lv[6] = (_Float16)(b.z - (float)hv[6]); lv[7] = (_Float16)(b.w - (float)hv[7]);
}

// ------- transpose + split weights via LDS tile: W[h][f][d] -> Wt hi/lo [h][d][f] -------
__global__ void split_w_kernel(const float* __restrict__ W,
                               _Float16* __restrict__ thi, _Float16* __restrict__ tlo) {
  __shared__ float t[64][65];
  const int h = blockIdx.z, f0 = blockIdx.x * 64, d0 = blockIdx.y * 64;
  const int col = threadIdx.x & 63, rg = threadIdx.x >> 6;
#pragma unroll
  for (int it = 0; it < 16; ++it) {
    int f = rg * 16 + it;
    t[f][col] = W[((size_t)h * 256 + f0 + f) * 256 + d0 + col];
  }
  __syncthreads();
#pragma unroll
  for (int it = 0; it < 16; ++it) {
    int d = rg * 16 + it;
    float v = t[col][d];
    _Float16 hv = (_Float16)v;
    size_t idx = ((size_t)h * 256 + d0 + d) * 256 + f0 + col;
    thi[idx] = hv;
    tlo[idx] = (_Float16)(v - (float)hv);
  }
}

// ---------------- out = Cb broadcast ----------------
__global__ void out_init_kernel(float* __restrict__ out, const float* __restrict__ Cb) {
  int i = blockIdx.x * blockDim.x + threadIdx.x;
  if (i < B_ * S_ * 8) out[i] = Cb[i & 7];
}

// ---- projection GEMM (R10's best-measured config — FROZEN; R15 rewrite reverted:
// W-in-register variant regressed, +4x cached A-traffic and a 20.9ms stall mode) ----
// Template VMODE: 0: 3-mult, write hi+lo (q). 2: 3-mult, write hi only (k).
//                 1: single-mult, write f16 transposed [hb,D,S] (v).
template <int VMODE>
__global__ __launch_bounds__(256, 2) void proj_kernel(
    const float* __restrict__ A,
    const _Float16* __restrict__ Whi, const _Float16* __restrict__ Wlo,
    const float* __restrict__ bias, float oscale, int h0,
    _Float16* __restrict__ Ohi, _Float16* __restrict__ Olo) {
  constexpr bool TMULT = (VMODE != 1);
  __shared__ _Float16 a_hi[128 * VSTRIDE] __attribute__((aligned(16)));
  __shared__ _Float16 b_hi[128 * VSTRIDE] __attribute__((aligned(16)));
  __shared__ _Float16 a_lo[TMULT ? 128 * VSTRIDE : 8] __attribute__((aligned(16)));
  __shared__ _Float16 b_lo[TMULT ? 128 * VSTRIDE : 8] __attribute__((aligned(16)));
  const int tid = threadIdx.x;
  const int w = tid >> 6, lane = tid & 63;
  const int quad = lane >> 4, l15 = lane & 15;
  const int hb = blockIdx.z, h = h0 + (hb >> 3), b = hb & 7;
  const int s0 = blockIdx.x * 128, d0 = blockIdx.y * 128;
  const int wr = w >> 1, wc = w & 1;
  const f32x4 fz = {0.f, 0.f, 0.f, 0.f};
  f32x4 acc[4][4];
#pragma unroll
  for (int i = 0; i < 4; ++i)
#pragma unroll
    for (int j = 0; j < 4; ++j) acc[i][j] = fz;
  const size_t arow0 = (size_t)b * S_ + s0;
  const size_t wrow0 = (size_t)h * 256 + d0;
  for (int kk = 0; kk < 8; ++kk) {
    const int f0 = kk * 32;
    __syncthreads();
#pragma unroll
    for (int i = 0; i < 2; ++i) {
      int cc = i * 256 + tid;
      int r = cc >> 2, ch = (cc & 3) * 8;
      half8 hv, lv;
      split8(A + (arow0 + r) * 256 + f0 + ch, hv, lv);
      *(half8*)&a_hi[r * VSTRIDE + ch] = hv;
      size_t woff = (wrow0 + r) * 256 + f0 + ch;
      *(half8*)&b_hi[r * VSTRIDE + ch] = *(const half8*)(Whi + woff);
      if (TMULT) {
        *(half8*)&a_lo[r * VSTRIDE + ch] = lv;
        *(half8*)&b_lo[r * VSTRIDE + ch] = *(const half8*)(Wlo + woff);
      }
    }
    __syncthreads();
    half8 afh[4], afl[4], bfh[4], bfl[4];
#pragma unroll
    for (int t = 0; t < 4; ++t) {
      int ar = wr * 64 + t * 16 + l15;
      afh[t] = *(const half8*)&a_hi[ar * VSTRIDE + quad * 8];
      int br = wc * 64 + t * 16 + l15;
      bfh[t] = *(const half8*)&b_hi[br * VSTRIDE + quad * 8];
      if (TMULT) {
        afl[t] = *(const half8*)&a_lo[ar * VSTRIDE + quad * 8];
        bfl[t] = *(const half8*)&b_lo[br * VSTRIDE + quad * 8];
      }
    }
#pragma unroll
    for (int rf = 0; rf < 4; ++rf)
#pragma unroll
      for (int cf = 0; cf < 4; ++cf) {
        acc[rf][cf] = __builtin_amdgcn_mfma_f32_16x16x32_f16(afh[rf], bfh[cf], acc[rf][cf], 0, 0, 0);
        if (TMULT) {
          acc[rf][cf] = __builtin_amdgcn_mfma_f32_16x16x32_f16(afh[rf], bfl[cf], acc[rf][cf], 0, 0, 0);
          acc[rf][cf] = __builtin_amdgcn_mfma_f32_16x16x32_f16(afl[rf], bfh[cf], acc[rf][cf], 0, 0, 0);
        }
      }
  }
  // epilogue: C/D layout row = quad*4+reg (s), col = lane&15 (d)
#pragma unroll
  for (int rf = 0; rf < 4; ++rf) {
#pragma unroll
    for (int cf = 0; cf < 4; ++cf) {
      const int d = d0 + wc * 64 + cf * 16 + l15;
      const float bv = bias[h * 256 + d];
      if (VMODE != 1) {
#pragma unroll
        for (int r = 0; r < 4; ++r) {
          const int s = s0 + wr * 64 + rf * 16 + quad * 4 + r;
          float val = (acc[rf][cf][r] + bv) * oscale;
          _Float16 hvv = (_Float16)val;
          size_t idx = ((size_t)hb * S_ + s) * 256 + d;
          Ohi[idx] = hvv;
          if (VMODE == 0) Olo[idx] = (_Float16)(val - (float)hvv);
        }
      } else {
        // lane holds 4 consecutive s for fixed d -> coalesced half4 store along S
        half4v pack;
#pragma unroll
        for (int r = 0; r < 4; ++r) pack[r] = (_Float16)((acc[rf][cf][r] + bv) * oscale);
        size_t idx = ((size_t)hb * 256 + d) * S_ + s0 + wr * 64 + rf * 16 + quad * 4;
        *(half4v*)(Ohi + idx) = pack;
      }
    }
  }
}

// pack 2 f32 -> 2 f16 (round-nearest, matches prior numerics) in one 32b word
__device__ inline unsigned int pack2(float a, float b) {
  half2v h; h[0] = (_Float16)a; h[1] = (_Float16)b;
  return __builtin_bit_cast(unsigned int, h);
}

// ---------------- flash attention + fused C-projection — R16: 32x32 MFMA ----------------
// LDS-read-bound before (84% model): every wave read whole K/V tile at 4 MAC/byte.
// 32x32x16 MFMA = 8 MAC/byte: 2-wave blocks, wave owns 32 q-rows; per-q LDS halved.
// Swapped mfma(K,Q): C col = lane&31 = q (lane-local softmax, 2 xor32 shfls);
// P -> PV A-frag built in registers (pack + xor32 half-exchange) — no P LDS, 2 barriers.
// T14 reg-staging: kt+1 global loads issued before kt compute (1 wave/SIMD occupancy).
// Defer-max THR=8: skip O-rescale unless a q's tile-max beats running max by >8.
__global__ __launch_bounds__(128) void flash_kernel(
    const _Float16* __restrict__ qhi, const _Float16* __restrict__ qlo,
    const _Float16* __restrict__ khi,
    const _Float16* __restrict__ vt, const float* __restrict__ Cw,
    float* __restrict__ out, int h0) {
  __shared__ _Float16 khi_s[32 * KSTRIDE] __attribute__((aligned(16)));
  __shared__ _Float16 vt_s[256 * VSTRIDE] __attribute__((aligned(16)));
  const int tid = threadIdx.x, wq = tid >> 6, lane = tid & 63;
  const int l31 = lane & 31, hh = lane >> 5;
  const int hb = blockIdx.y, head = h0 + (hb >> 3), b = hb & 7;
  const int qbase = blockIdx.x * 64 + wq * 32;
  // Q B-frags: col = l31 (q-row), k-halves = hh*8+j within 16-wide d-step s
  half8 qfh[16], qfl[16];
  {
    size_t qrow = (size_t)hb * S_ + qbase + l31;
    const _Float16* qh = qhi + qrow * 256 + hh * 8;
    const _Float16* ql = qlo + qrow * 256 + hh * 8;
#pragma unroll
    for (int s = 0; s < 16; ++s) {
      qfh[s] = *(const half8*)(qh + s * 16);
      qfl[s] = *(const half8*)(ql + s * 16);
    }
  }
  f32x16 o_acc[8];
#pragma unroll
  for (int dt = 0; dt < 8; ++dt)
#pragma unroll
    for (int r = 0; r < 16; ++r) o_acc[dt][r] = 0.f;
  float m_r = -3.0e38f, l_r = 0.f;

  // reg-staged K/V tile (T14): 16 chunks/thread
  half8 stK[8], stV[8];
  const size_t vrow = ((size_t)hb * 256 + (tid >> 2) * 8 / 8) * 0;  // (unused, kept simple below)
  auto LOADKV = [&](int kt) {
    size_t kbase = ((size_t)hb * S_ + (size_t)kt * 32) * 256;
#pragma unroll
    for (int i = 0; i < 8; ++i) {
      int c = i * 128 + tid;
      stK[i] = *(const half8*)(khi + kbase + (c >> 5) * 256 + (c & 31) * 8);
    }
#pragma unroll
    for (int i = 0; i < 8; ++i) {
      int c = i * 128 + tid;
      stV[i] = *(const half8*)(vt + ((size_t)hb * 256 + (c >> 2)) * S_ + (size_t)kt * 32 + (c & 3) * 8);
    }
  };
  LOADKV(0);

  for (int kt = 0; kt < 64; ++kt) {
    __syncthreads();  // prior iteration's LDS reads done
    // write staged regs to LDS
#pragma unroll
    for (int i = 0; i < 8; ++i) {
      int c = i * 128 + tid;
      *(half8*)&khi_s[(c >> 5) * KSTRIDE + (c & 31) * 8] = stK[i];
    }
#pragma unroll
    for (int i = 0; i < 8; ++i) {
      int c = i * 128 + tid;
      *(half8*)&vt_s[(c >> 2) * VSTRIDE + (c & 3) * 8] = stV[i];
    }
    if (kt < 63) LOADKV(kt + 1);  // issue next tile's loads; complete under compute
    __syncthreads();
    // QK^T swapped: A = K rows (kv), B = Q. C: col = l31 = q; row k = (r&3)+8*(r>>2)+4*hh
    f32x16 sc;
#pragma unroll
    for (int r = 0; r < 16; ++r) sc[r] = 0.f;
#pragma unroll
    for (int s = 0; s < 16; ++s) {
      half8 kf = *(const half8*)&khi_s[l31 * KSTRIDE + s * 16 + hh * 8];
      sc = __builtin_amdgcn_mfma_f32_32x32x16_f16(kf, qfh[s], sc, 0, 0, 0);
      sc = __builtin_amdgcn_mfma_f32_32x32x16_f16(kf, qfl[s], sc, 0, 0, 0);
    }
    // online softmax for q = l31: 16 in-lane k + partner half via xor32
    float vmax = sc[0];
#pragma unroll
    for (int r = 1; r < 16; ++r) vmax = fmaxf(vmax, sc[r]);
    vmax = fmaxf(vmax, __shfl_xor(vmax, 32));
    if (__any(vmax > m_r + 8.0f)) {
      float mn = fmaxf(m_r, vmax);
      float al = __expf(m_r - mn);
      m_r = mn;
      l_r *= al;
#pragma unroll
      for (int r = 0; r < 16; ++r) {
        int q = (r & 3) + 8 * (r >> 2) + 4 * hh;
        float alq = __shfl(al, q);
#pragma unroll
        for (int dt = 0; dt < 8; ++dt) o_acc[dt][r] *= alq;
      }
    }
    float p[16], ss = 0.f;
#pragma unroll
    for (int r = 0; r < 16; ++r) { p[r] = __expf(sc[r] - m_r); ss += p[r]; }
    ss += __shfl_xor(ss, 32);
    l_r += ss;
    // build PV A-frags in registers: lane needs P[q=l31][k = 16s + 8*hh + j]
    // own regs hold k = (r&3)+8*(r>>2)+4*hh; partner (xor32) holds the complement.
    unsigned int wA[8];
#pragma unroll
    for (int i = 0; i < 8; ++i) wA[i] = pack2(p[2 * i], p[2 * i + 1]);
    unsigned int t0 = __shfl_xor(wA[0], 32), t1 = __shfl_xor(wA[1], 32);
    unsigned int t2 = __shfl_xor(wA[2], 32), t3 = __shfl_xor(wA[3], 32);
    unsigned int t4 = __shfl_xor(wA[4], 32), t5 = __shfl_xor(wA[5], 32);
    unsigned int t6 = __shfl_xor(wA[6], 32), t7 = __shfl_xor(wA[7], 32);
    union U { unsigned int u[4]; half8 h; };
    U u0, u1;
    u0.u[0] = hh ? t2 : wA[0];
    u0.u[1] = hh ? t3 : wA[1];
    u0.u[2] = hh ? wA[2] : t0;
    u0.u[3] = hh ? wA[3] : t1;
    u1.u[0] = hh ? t6 : wA[4];
    u1.u[1] = hh ? t7 : wA[5];
    u1.u[2] = hh ? wA[6] : t4;
    u1.u[3] = hh ? wA[7] : t5;
    half8 pa0 = u0.h, pa1 = u1.h;
    // PV: A = P (row=q=l31), B = V^T tile (col d = dt*32+l31, k = 16s+8hh+j)
#pragma unroll
    for (int dt = 0; dt < 8; ++dt) {
      half8 vf0 = *(const half8*)&vt_s[(dt * 32 + l31) * VSTRIDE + hh * 8];
      o_acc[dt] = __builtin_amdgcn_mfma_f32_32x32x16_f16(pa0, vf0, o_acc[dt], 0, 0, 0);
      half8 vf1 = *(const half8*)&vt_s[(dt * 32 + l31) * VSTRIDE + 16 + hh * 8];
      o_acc[dt] = __builtin_amdgcn_mfma_f32_32x32x16_f16(pa1, vf1, o_acc[dt], 0, 0, 0);
    }
  }
  // epilogue: normalize + fused C-projection. O C-layout: row q = (r&3)+8*(r>>2)+4*hh,
  // col d = dt*32 + l31. part[q-reg r][j] = sum_d o*Cw; reduce over d-lanes per half.
  float rcl[16];
#pragma unroll
  for (int r = 0; r < 16; ++r) {
    int q = (r & 3) + 8 * (r >> 2) + 4 * hh;
    rcl[r] = 1.0f / __shfl(l_r, q);
  }
  float part[128];
#pragma unroll
  for (int i = 0; i < 128; ++i) part[i] = 0.f;
#pragma unroll
  for (int dt = 0; dt < 8; ++dt) {
    const float4* cwv = (const float4*)(Cw + ((size_t)head * 256 + dt * 32 + l31) * 8);
    float4 c0 = cwv[0], c1 = cwv[1];
#pragma unroll
    for (int r = 0; r < 16; ++r) {
      float ov = o_acc[dt][r] * rcl[r];
      part[r * 8 + 0] += ov * c0.x;
      part[r * 8 + 1] += ov * c0.y;
      part[r * 8 + 2] += ov * c0.z;
      part[r * 8 + 3] += ov * c0.w;
      part[r * 8 + 4] += ov * c1.x;
      part[r * 8 + 5] += ov * c1.y;
      part[r * 8 + 6] += ov * c1.z;
      part[r * 8 + 7] += ov * c1.w;
    }
  }
  // butterfly sum over the 32 lanes of each half (xor strides < 32 stay in-half)
#pragma unroll
  for (int i = 0; i < 128; ++i) {
    float v = part[i];
    v += __shfl_xor(v, 1);
    v += __shfl_xor(v, 2);
    v += __shfl_xor(v, 4);
    v += __shfl_xor(v, 8);
    v += __shfl_xor(v, 16);
    part[i] = v;
  }
  // distributed static-indexed atomics: lane l31 == idx>>2 writes idx (both halves,
  // different q via hh). 4 atomics per lane.
#pragma unroll
  for (int idx = 0; idx < 128; ++idx) {
    if (l31 == (idx >> 2)) {
      int r = idx >> 3, j = idx & 7;
      int q = (r & 3) + 8 * (r >> 2) + 4 * hh;
      atomicAdd(&out[((size_t)b * S_ + qbase + q) * 8 + j], part[idx]);
    }
  }
}

extern "C" void kernel_launch(void* const* d_in, const int* in_sizes, int n_in,
                              void* d_out, int out_size, void* d_ws, size_t ws_size,
                              hipStream_t stream) {
  const float* x  = (const float*)d_in[0];
  const float* bo = (const float*)d_in[1];
  const float* Qw = (const float*)d_in[2];
  const float* Qb = (const float*)d_in[3];
  const float* Kw = (const float*)d_in[4];
  const float* Kb = (const float*)d_in[5];
  const float* Vw = (const float*)d_in[6];
  const float* Vb = (const float*)d_in[7];
  const float* Cw = (const float*)d_in[8];
  const float* Cb = (const float*)d_in[9];
  float* out = (float*)d_out;

  const size_t NW  = (size_t)H_ * 256 * 256;
  const size_t NHB = (size_t)B_ * S_ * 256;
  const size_t ALN = 256;
  auto pad = [](size_t b) { return (b + 255) & ~(size_t)255; };

  // pick largest head-chunk HC in {8,4,2,1} whose scratch fits ws_size
  int HC = 8;
  while (HC > 1) {
    size_t need = 6 * pad(NW * 2) + 4 * pad((size_t)HC * NHB * 2) + ALN;
    if (need <= ws_size) break;
    HC >>= 1;
  }

  char* base = (char*)d_ws;
  size_t off = 0;
  auto carve = [&](size_t nelem) -> _Float16* {
    _Float16* p = (_Float16*)(base + off);
    off += pad(nelem * 2);
    return p;
  };
  _Float16* qwt_hi = carve(NW); _Float16* qwt_lo = carve(NW);
  _Float16* kwt_hi = carve(NW); _Float16* kwt_lo = carve(NW);
  _Float16* vwt_hi = carve(NW); _Float16* vwt_lo = carve(NW);
  const size_t NC = (size_t)HC * NHB;
  _Float16* q_hi = carve(NC); _Float16* q_lo = carve(NC);
  _Float16* k_hi = carve(NC);
  _Float16* v_t  = carve(NC);

  dim3 wg(4, 4, 8);
  split_w_kernel<<<wg, 256, 0, stream>>>(Qw, qwt_hi, qwt_lo);
  split_w_kernel<<<wg, 256, 0, stream>>>(Kw, kwt_hi, kwt_lo);
  split_w_kernel<<<wg, 256, 0, stream>>>(Vw, vwt_hi, vwt_lo);
  out_init_kernel<<<(B_ * S_ * 8) / 256, 256, 0, stream>>>(out, Cb);

  for (int h0 = 0; h0 < H_; h0 += HC) {
    dim3 pg(16, 2, HC * 8);
    // q: fold softmax scale 1/sqrt(256)=1/16 into the projection output
    proj_kernel<0><<<pg, 256, 0, stream>>>(bo, qwt_hi, qwt_lo, Qb, 0.0625f, h0, q_hi, q_lo);
    proj_kernel<2><<<pg, 256, 0, stream>>>(x, kwt_hi, kwt_lo, Kb, 1.0f, h0, k_hi, nullptr);
    proj_kernel<1><<<pg, 256, 0, stream>>>(x, vwt_hi, vwt_lo, Vb, 1.0f, h0, v_t, nullptr);
    dim3 fg(32, HC * 8);
    flash_kernel<<<fg, 128, 0, stream>>>(q_hi, q_lo, k_hi, v_t, Cw, out, h0);
  }
}

// Round 4
// 1372.052 us; speedup vs baseline: 1.0790x; 1.0790x over previous
//
#include <hip/hip_runtime.h>

#define H_ 8
#define B_ 8
#define S_ 2048
#define D_ 256

// padded LDS strides (halves): kill 8/16-way bank conflicts, keep 16B alignment
#define KSTRIDE 264   // k-tile rows: 528B = 4 banks offset/row
#define VSTRIDE 40    // 32-col tiles: 80B = 20 banks offset/row

typedef __attribute__((ext_vector_type(8))) _Float16 half8;
typedef __attribute__((ext_vector_type(4))) _Float16 half4v;
typedef __attribute__((ext_vector_type(2))) _Float16 half2v;
typedef __attribute__((ext_vector_type(4))) float f32x4;
typedef __attribute__((ext_vector_type(16))) float f32x16;

// split 8 consecutive fp32 into fp16 hi + lo residual
__device__ inline void split8(const float* __restrict__ p, half8& hv, half8& lv) {
  float4 a = *(const float4*)p, b = *(const float4*)(p + 4);
  hv[0] = (_Float16)a.x; hv[1] = (_Float16)a.y; hv[2] = (_Float16)a.z; hv[3] = (_Float16)a.w;
  hv[4] = (_Float16)b.x; hv[5] = (_Float16)b.y; hv[6] = (_Float16)b.z; hv[7] = (_Float16)b.w;
  lv[0] = (_Float16)(a.x - (float)hv[0]); lv[1] = (_Float16)(a.y - (float)hv[1]);
  lv[2] = (_Float16)(a.z - (float)hv[2]); lv[3] = (_Float16)(a.w - (float)hv[3]);
  lv[4] = (_Float16)(b.x - (float)hv[4]); lv[5] = (_Float16)(b.y - (float)hv[5]);
  lv[6] = (_Float16)(b.z - (float)hv[6]); lv[7] = (_Float16)(b.w - (float)hv[7]);
}

// ------- transpose + split weights via LDS tile: W[h][f][d] -> Wt hi/lo [h][d][f] -------
__global__ void split_w_kernel(const float* __restrict__ W,
                               _Float16* __restrict__ thi, _Float16* __restrict__ tlo) {
  __shared__ float t[64][65];
  const int h = blockIdx.z, f0 = blockIdx.x * 64, d0 = blockIdx.y * 64;
  const int col = threadIdx.x & 63, rg = threadIdx.x >> 6;
#pragma unroll
  for (int it = 0; it < 16; ++it) {
    int f = rg * 16 + it;
    t[f][col] = W[((size_t)h * 256 + f0 + f) * 256 + d0 + col];
  }
  __syncthreads();
#pragma unroll
  for (int it = 0; it < 16; ++it) {
    int d = rg * 16 + it;
    float v = t[col][d];
    _Float16 hv = (_Float16)v;
    size_t idx = ((size_t)h * 256 + d0 + d) * 256 + f0 + col;
    thi[idx] = hv;
    tlo[idx] = (_Float16)(v - (float)hv);
  }
}

// ---------------- out = Cb broadcast ----------------
__global__ void out_init_kernel(float* __restrict__ out, const float* __restrict__ Cb) {
  int i = blockIdx.x * blockDim.x + threadIdx.x;
  if (i < B_ * S_ * 8) out[i] = Cb[i & 7];
}

// ---- projection GEMM (R10's best-measured config — FROZEN; R15 W-in-reg rewrite
// regressed and was reverted) ----
// Template VMODE: 0: 3-mult, write hi+lo (q). 2: 3-mult, write hi only (k).
//                 1: single-mult, write f16 transposed [hb,D,S] (v).
template <int VMODE>
__global__ __launch_bounds__(256, 2) void proj_kernel(
    const float* __restrict__ A,
    const _Float16* __restrict__ Whi, const _Float16* __restrict__ Wlo,
    const float* __restrict__ bias, float oscale, int h0,
    _Float16* __restrict__ Ohi, _Float16* __restrict__ Olo) {
  constexpr bool TMULT = (VMODE != 1);
  __shared__ _Float16 a_hi[128 * VSTRIDE] __attribute__((aligned(16)));
  __shared__ _Float16 b_hi[128 * VSTRIDE] __attribute__((aligned(16)));
  __shared__ _Float16 a_lo[TMULT ? 128 * VSTRIDE : 8] __attribute__((aligned(16)));
  __shared__ _Float16 b_lo[TMULT ? 128 * VSTRIDE : 8] __attribute__((aligned(16)));
  const int tid = threadIdx.x;
  const int w = tid >> 6, lane = tid & 63;
  const int quad = lane >> 4, l15 = lane & 15;
  const int hb = blockIdx.z, h = h0 + (hb >> 3), b = hb & 7;
  const int s0 = blockIdx.x * 128, d0 = blockIdx.y * 128;
  const int wr = w >> 1, wc = w & 1;
  const f32x4 fz = {0.f, 0.f, 0.f, 0.f};
  f32x4 acc[4][4];
#pragma unroll
  for (int i = 0; i < 4; ++i)
#pragma unroll
    for (int j = 0; j < 4; ++j) acc[i][j] = fz;
  const size_t arow0 = (size_t)b * S_ + s0;
  const size_t wrow0 = (size_t)h * 256 + d0;
  for (int kk = 0; kk < 8; ++kk) {
    const int f0 = kk * 32;
    __syncthreads();
#pragma unroll
    for (int i = 0; i < 2; ++i) {
      int cc = i * 256 + tid;
      int r = cc >> 2, ch = (cc & 3) * 8;
      half8 hv, lv;
      split8(A + (arow0 + r) * 256 + f0 + ch, hv, lv);
      *(half8*)&a_hi[r * VSTRIDE + ch] = hv;
      size_t woff = (wrow0 + r) * 256 + f0 + ch;
      *(half8*)&b_hi[r * VSTRIDE + ch] = *(const half8*)(Whi + woff);
      if (TMULT) {
        *(half8*)&a_lo[r * VSTRIDE + ch] = lv;
        *(half8*)&b_lo[r * VSTRIDE + ch] = *(const half8*)(Wlo + woff);
      }
    }
    __syncthreads();
    half8 afh[4], afl[4], bfh[4], bfl[4];
#pragma unroll
    for (int t = 0; t < 4; ++t) {
      int ar = wr * 64 + t * 16 + l15;
      afh[t] = *(const half8*)&a_hi[ar * VSTRIDE + quad * 8];
      int br = wc * 64 + t * 16 + l15;
      bfh[t] = *(const half8*)&b_hi[br * VSTRIDE + quad * 8];
      if (TMULT) {
        afl[t] = *(const half8*)&a_lo[ar * VSTRIDE + quad * 8];
        bfl[t] = *(const half8*)&b_lo[br * VSTRIDE + quad * 8];
      }
    }
#pragma unroll
    for (int rf = 0; rf < 4; ++rf)
#pragma unroll
      for (int cf = 0; cf < 4; ++cf) {
        acc[rf][cf] = __builtin_amdgcn_mfma_f32_16x16x32_f16(afh[rf], bfh[cf], acc[rf][cf], 0, 0, 0);
        if (TMULT) {
          acc[rf][cf] = __builtin_amdgcn_mfma_f32_16x16x32_f16(afh[rf], bfl[cf], acc[rf][cf], 0, 0, 0);
          acc[rf][cf] = __builtin_amdgcn_mfma_f32_16x16x32_f16(afl[rf], bfh[cf], acc[rf][cf], 0, 0, 0);
        }
      }
  }
  // epilogue: C/D layout row = quad*4+reg (s), col = lane&15 (d)
#pragma unroll
  for (int rf = 0; rf < 4; ++rf) {
#pragma unroll
    for (int cf = 0; cf < 4; ++cf) {
      const int d = d0 + wc * 64 + cf * 16 + l15;
      const float bv = bias[h * 256 + d];
      if (VMODE != 1) {
#pragma unroll
        for (int r = 0; r < 4; ++r) {
          const int s = s0 + wr * 64 + rf * 16 + quad * 4 + r;
          float val = (acc[rf][cf][r] + bv) * oscale;
          _Float16 hvv = (_Float16)val;
          size_t idx = ((size_t)hb * S_ + s) * 256 + d;
          Ohi[idx] = hvv;
          if (VMODE == 0) Olo[idx] = (_Float16)(val - (float)hvv);
        }
      } else {
        // lane holds 4 consecutive s for fixed d -> coalesced half4 store along S
        half4v pack;
#pragma unroll
        for (int r = 0; r < 4; ++r) pack[r] = (_Float16)((acc[rf][cf][r] + bv) * oscale);
        size_t idx = ((size_t)hb * 256 + d) * S_ + s0 + wr * 64 + rf * 16 + quad * 4;
        *(half4v*)(Ohi + idx) = pack;
      }
    }
  }
}

// pack 2 f32 -> 2 f16 (round-nearest, matches prior numerics) in one 32b word
__device__ inline unsigned int pack2(float a, float b) {
  half2v h; h[0] = (_Float16)a; h[1] = (_Float16)b;
  return __builtin_bit_cast(unsigned int, h);
}

// ---------------- flash attention + fused C-projection — R17: 32x32 MFMA, 512-VGPR ----
// R16 structure was right (conflicts 4.5e7 -> 8.4e6) but compiler capped VGPR at 256
// with default launch_bounds(128) -> per-kt scratch spills (WRITE 16->39MB, latency
// collapse, 655us). Fix: __launch_bounds__(128, 1) unlocks the unified 512-reg file
// at 1 wave/SIMD. Live state ~390 regs (Q-frags 128 + o_acc 128 + staging 64 + temps).
// LDS model: 768 cyc/blk-kt (staging 256 + 32 b128 reads 512) -> ~164us floor vs
// R1's 1690 -> 337us measured. Occupancy 4 waves/CU (2 blocks x 2 waves) is the
// expected steady state; LDS stays the wall, not latency.
__global__ __launch_bounds__(128, 1) void flash_kernel(
    const _Float16* __restrict__ qhi, const _Float16* __restrict__ qlo,
    const _Float16* __restrict__ khi,
    const _Float16* __restrict__ vt, const float* __restrict__ Cw,
    float* __restrict__ out, int h0) {
  __shared__ _Float16 khi_s[32 * KSTRIDE] __attribute__((aligned(16)));
  __shared__ _Float16 vt_s[256 * VSTRIDE] __attribute__((aligned(16)));
  const int tid = threadIdx.x, wq = tid >> 6, lane = tid & 63;
  const int l31 = lane & 31, hh = lane >> 5;
  const int hb = blockIdx.y, head = h0 + (hb >> 3), b = hb & 7;
  const int qbase = blockIdx.x * 64 + wq * 32;
  // Q B-frags: col = l31 (q-row), k-halves = hh*8+j within 16-wide d-step s
  half8 qfh[16], qfl[16];
  {
    size_t qrow = (size_t)hb * S_ + qbase + l31;
    const _Float16* qh = qhi + qrow * 256 + hh * 8;
    const _Float16* ql = qlo + qrow * 256 + hh * 8;
#pragma unroll
    for (int s = 0; s < 16; ++s) {
      qfh[s] = *(const half8*)(qh + s * 16);
      qfl[s] = *(const half8*)(ql + s * 16);
    }
  }
  f32x16 o_acc[8];
#pragma unroll
  for (int dt = 0; dt < 8; ++dt)
#pragma unroll
    for (int r = 0; r < 16; ++r) o_acc[dt][r] = 0.f;
  float m_r = -3.0e38f, l_r = 0.f;

  // reg-staged K/V tile (T14): 16 half8 chunks/thread, 64 VGPR
  half8 stK[8], stV[8];
  auto LOADKV = [&](int kt) {
    size_t kbase = ((size_t)hb * S_ + (size_t)kt * 32) * 256;
#pragma unroll
    for (int i = 0; i < 8; ++i) {
      int c = i * 128 + tid;
      stK[i] = *(const half8*)(khi + kbase + (c >> 5) * 256 + (c & 31) * 8);
    }
#pragma unroll
    for (int i = 0; i < 8; ++i) {
      int c = i * 128 + tid;
      stV[i] = *(const half8*)(vt + ((size_t)hb * 256 + (c >> 2)) * S_ + (size_t)kt * 32 + (c & 3) * 8);
    }
  };
  LOADKV(0);

  for (int kt = 0; kt < 64; ++kt) {
    __syncthreads();  // prior iteration's LDS reads done
    // write staged regs to LDS
#pragma unroll
    for (int i = 0; i < 8; ++i) {
      int c = i * 128 + tid;
      *(half8*)&khi_s[(c >> 5) * KSTRIDE + (c & 31) * 8] = stK[i];
    }
#pragma unroll
    for (int i = 0; i < 8; ++i) {
      int c = i * 128 + tid;
      *(half8*)&vt_s[(c >> 2) * VSTRIDE + (c & 3) * 8] = stV[i];
    }
    if (kt < 63) LOADKV(kt + 1);  // issue next tile's loads; complete under compute
    __syncthreads();
    // QK^T swapped: A = K rows (kv), B = Q. C: col = l31 = q; row k = (r&3)+8*(r>>2)+4*hh
    f32x16 sc;
#pragma unroll
    for (int r = 0; r < 16; ++r) sc[r] = 0.f;
#pragma unroll
    for (int s = 0; s < 16; ++s) {
      half8 kf = *(const half8*)&khi_s[l31 * KSTRIDE + s * 16 + hh * 8];
      sc = __builtin_amdgcn_mfma_f32_32x32x16_f16(kf, qfh[s], sc, 0, 0, 0);
      sc = __builtin_amdgcn_mfma_f32_32x32x16_f16(kf, qfl[s], sc, 0, 0, 0);
    }
    // online softmax for q = l31: 16 in-lane k + partner half via xor32
    float vmax = sc[0];
#pragma unroll
    for (int r = 1; r < 16; ++r) vmax = fmaxf(vmax, sc[r]);
    vmax = fmaxf(vmax, __shfl_xor(vmax, 32));
    if (__any(vmax > m_r + 8.0f)) {
      float mn = fmaxf(m_r, vmax);
      float al = __expf(m_r - mn);
      m_r = mn;
      l_r *= al;
#pragma unroll
      for (int r = 0; r < 16; ++r) {
        int q = (r & 3) + 8 * (r >> 2) + 4 * hh;
        float alq = __shfl(al, q);
#pragma unroll
        for (int dt = 0; dt < 8; ++dt) o_acc[dt][r] *= alq;
      }
    }
    float ss = 0.f;
#pragma unroll
    for (int r = 0; r < 16; ++r) { sc[r] = __expf(sc[r] - m_r); ss += sc[r]; }
    ss += __shfl_xor(ss, 32);
    l_r += ss;
    // build PV A-frags in registers: lane needs P[q=l31][k = 16s + 8*hh + j]
    // own regs hold k = (r&3)+8*(r>>2)+4*hh; partner (xor32) holds the complement.
    unsigned int wA[8];
#pragma unroll
    for (int i = 0; i < 8; ++i) wA[i] = pack2(sc[2 * i], sc[2 * i + 1]);
    unsigned int t0 = __shfl_xor(wA[0], 32), t1 = __shfl_xor(wA[1], 32);
    unsigned int t2 = __shfl_xor(wA[2], 32), t3 = __shfl_xor(wA[3], 32);
    unsigned int t4 = __shfl_xor(wA[4], 32), t5 = __shfl_xor(wA[5], 32);
    unsigned int t6 = __shfl_xor(wA[6], 32), t7 = __shfl_xor(wA[7], 32);
    union U { unsigned int u[4]; half8 h; };
    U u0, u1;
    u0.u[0] = hh ? t2 : wA[0];
    u0.u[1] = hh ? t3 : wA[1];
    u0.u[2] = hh ? wA[2] : t0;
    u0.u[3] = hh ? wA[3] : t1;
    u1.u[0] = hh ? t6 : wA[4];
    u1.u[1] = hh ? t7 : wA[5];
    u1.u[2] = hh ? wA[6] : t4;
    u1.u[3] = hh ? wA[7] : t5;
    half8 pa0 = u0.h, pa1 = u1.h;
    // PV: A = P (row=q=l31), B = V^T tile (col d = dt*32+l31, k = 16s+8hh+j)
#pragma unroll
    for (int dt = 0; dt < 8; ++dt) {
      half8 vf0 = *(const half8*)&vt_s[(dt * 32 + l31) * VSTRIDE + hh * 8];
      o_acc[dt] = __builtin_amdgcn_mfma_f32_32x32x16_f16(pa0, vf0, o_acc[dt], 0, 0, 0);
      half8 vf1 = *(const half8*)&vt_s[(dt * 32 + l31) * VSTRIDE + 16 + hh * 8];
      o_acc[dt] = __builtin_amdgcn_mfma_f32_32x32x16_f16(pa1, vf1, o_acc[dt], 0, 0, 0);
    }
  }
  // epilogue: normalize + fused C-projection. O C-layout: row q = (r&3)+8*(r>>2)+4*hh,
  // col d = dt*32 + l31. part[q-reg r][j] = sum_d o*Cw; reduce over d-lanes per half.
  float rcl[16];
#pragma unroll
  for (int r = 0; r < 16; ++r) {
    int q = (r & 3) + 8 * (r >> 2) + 4 * hh;
    rcl[r] = 1.0f / __shfl(l_r, q);
  }
  float part[128];
#pragma unroll
  for (int i = 0; i < 128; ++i) part[i] = 0.f;
#pragma unroll
  for (int dt = 0; dt < 8; ++dt) {
    const float4* cwv = (const float4*)(Cw + ((size_t)head * 256 + dt * 32 + l31) * 8);
    float4 c0 = cwv[0], c1 = cwv[1];
#pragma unroll
    for (int r = 0; r < 16; ++r) {
      float ov = o_acc[dt][r] * rcl[r];
      part[r * 8 + 0] += ov * c0.x;
      part[r * 8 + 1] += ov * c0.y;
      part[r * 8 + 2] += ov * c0.z;
      part[r * 8 + 3] += ov * c0.w;
      part[r * 8 + 4] += ov * c1.x;
      part[r * 8 + 5] += ov * c1.y;
      part[r * 8 + 6] += ov * c1.z;
      part[r * 8 + 7] += ov * c1.w;
    }
  }
  // butterfly sum over the 32 lanes of each half (xor strides < 32 stay in-half)
#pragma unroll
  for (int i = 0; i < 128; ++i) {
    float v = part[i];
    v += __shfl_xor(v, 1);
    v += __shfl_xor(v, 2);
    v += __shfl_xor(v, 4);
    v += __shfl_xor(v, 8);
    v += __shfl_xor(v, 16);
    part[i] = v;
  }
  // distributed static-indexed atomics: lane l31 == idx>>2 writes idx (both halves,
  // different q via hh). 4 atomics per lane.
#pragma unroll
  for (int idx = 0; idx < 128; ++idx) {
    if (l31 == (idx >> 2)) {
      int r = idx >> 3, j = idx & 7;
      int q = (r & 3) + 8 * (r >> 2) + 4 * hh;
      atomicAdd(&out[((size_t)b * S_ + qbase + q) * 8 + j], part[idx]);
    }
  }
}

extern "C" void kernel_launch(void* const* d_in, const int* in_sizes, int n_in,
                              void* d_out, int out_size, void* d_ws, size_t ws_size,
                              hipStream_t stream) {
  const float* x  = (const float*)d_in[0];
  const float* bo = (const float*)d_in[1];
  const float* Qw = (const float*)d_in[2];
  const float* Qb = (const float*)d_in[3];
  const float* Kw = (const float*)d_in[4];
  const float* Kb = (const float*)d_in[5];
  const float* Vw = (const float*)d_in[6];
  const float* Vb = (const float*)d_in[7];
  const float* Cw = (const float*)d_in[8];
  const float* Cb = (const float*)d_in[9];
  float* out = (float*)d_out;

  const size_t NW  = (size_t)H_ * 256 * 256;
  const size_t NHB = (size_t)B_ * S_ * 256;
  const size_t ALN = 256;
  auto pad = [](size_t b) { return (b + 255) & ~(size_t)255; };

  // pick largest head-chunk HC in {8,4,2,1} whose scratch fits ws_size
  int HC = 8;
  while (HC > 1) {
    size_t need = 6 * pad(NW * 2) + 4 * pad((size_t)HC * NHB * 2) + ALN;
    if (need <= ws_size) break;
    HC >>= 1;
  }

  char* base = (char*)d_ws;
  size_t off = 0;
  auto carve = [&](size_t nelem) -> _Float16* {
    _Float16* p = (_Float16*)(base + off);
    off += pad(nelem * 2);
    return p;
  };
  _Float16* qwt_hi = carve(NW); _Float16* qwt_lo = carve(NW);
  _Float16* kwt_hi = carve(NW); _Float16* kwt_lo = carve(NW);
  _Float16* vwt_hi = carve(NW); _Float16* vwt_lo = carve(NW);
  const size_t NC = (size_t)HC * NHB;
  _Float16* q_hi = carve(NC); _Float16* q_lo = carve(NC);
  _Float16* k_hi = carve(NC);
  _Float16* v_t  = carve(NC);

  dim3 wg(4, 4, 8);
  split_w_kernel<<<wg, 256, 0, stream>>>(Qw, qwt_hi, qwt_lo);
  split_w_kernel<<<wg, 256, 0, stream>>>(Kw, kwt_hi, kwt_lo);
  split_w_kernel<<<wg, 256, 0, stream>>>(Vw, vwt_hi, vwt_lo);
  out_init_kernel<<<(B_ * S_ * 8) / 256, 256, 0, stream>>>(out, Cb);

  for (int h0 = 0; h0 < H_; h0 += HC) {
    dim3 pg(16, 2, HC * 8);
    // q: fold softmax scale 1/sqrt(256)=1/16 into the projection output
    proj_kernel<0><<<pg, 256, 0, stream>>>(bo, qwt_hi, qwt_lo, Qb, 0.0625f, h0, q_hi, q_lo);
    proj_kernel<2><<<pg, 256, 0, stream>>>(x, kwt_hi, kwt_lo, Kb, 1.0f, h0, k_hi, nullptr);
    proj_kernel<1><<<pg, 256, 0, stream>>>(x, vwt_hi, vwt_lo, Vb, 1.0f, h0, v_t, nullptr);
    dim3 fg(32, HC * 8);
    flash_kernel<<<fg, 128, 0, stream>>>(q_hi, q_lo, k_hi, v_t, Cw, out, h0);
  }
}

// Round 5
// 1056.141 us; speedup vs baseline: 1.4018x; 1.2991x over previous
//
#include <hip/hip_runtime.h>

#define H_ 8
#define B_ 8
#define S_ 2048
#define D_ 256

// padded LDS strides (halves): kill 8/16-way bank conflicts, keep 16B alignment
#define KSTRIDE 264   // k-tile rows: 528B = 4 banks offset/row
#define VSTRIDE 40    // 32-col tiles: 80B = 20 banks offset/row

typedef __attribute__((ext_vector_type(8))) _Float16 half8;
typedef __attribute__((ext_vector_type(4))) _Float16 half4v;
typedef __attribute__((ext_vector_type(2))) _Float16 half2v;
typedef __attribute__((ext_vector_type(4))) float f32x4;

// split 8 consecutive fp32 into fp16 hi + lo residual
__device__ inline void split8(const float* __restrict__ p, half8& hv, half8& lv) {
  float4 a = *(const float4*)p, b = *(const float4*)(p + 4);
  hv[0] = (_Float16)a.x; hv[1] = (_Float16)a.y; hv[2] = (_Float16)a.z; hv[3] = (_Float16)a.w;
  hv[4] = (_Float16)b.x; hv[5] = (_Float16)b.y; hv[6] = (_Float16)b.z; hv[7] = (_Float16)b.w;
  lv[0] = (_Float16)(a.x - (float)hv[0]); lv[1] = (_Float16)(a.y - (float)hv[1]);
  lv[2] = (_Float16)(a.z - (float)hv[2]); lv[3] = (_Float16)(a.w - (float)hv[3]);
  lv[4] = (_Float16)(b.x - (float)hv[4]); lv[5] = (_Float16)(b.y - (float)hv[5]);
  lv[6] = (_Float16)(b.z - (float)hv[6]); lv[7] = (_Float16)(b.w - (float)hv[7]);
}

// ------- transpose + split weights via LDS tile: W[h][f][d] -> Wt hi/lo [h][d][f] -------
__global__ void split_w_kernel(const float* __restrict__ W,
                               _Float16* __restrict__ thi, _Float16* __restrict__ tlo) {
  __shared__ float t[64][65];
  const int h = blockIdx.z, f0 = blockIdx.x * 64, d0 = blockIdx.y * 64;
  const int col = threadIdx.x & 63, rg = threadIdx.x >> 6;
#pragma unroll
  for (int it = 0; it < 16; ++it) {
    int f = rg * 16 + it;
    t[f][col] = W[((size_t)h * 256 + f0 + f) * 256 + d0 + col];
  }
  __syncthreads();
#pragma unroll
  for (int it = 0; it < 16; ++it) {
    int d = rg * 16 + it;
    float v = t[col][d];
    _Float16 hv = (_Float16)v;
    size_t idx = ((size_t)h * 256 + d0 + d) * 256 + f0 + col;
    thi[idx] = hv;
    tlo[idx] = (_Float16)(v - (float)hv);
  }
}

// ---------------- out = Cb broadcast ----------------
__global__ void out_init_kernel(float* __restrict__ out, const float* __restrict__ Cb) {
  int i = blockIdx.x * blockDim.x + threadIdx.x;
  if (i < B_ * S_ * 8) out[i] = Cb[i & 7];
}

// ---- projection GEMM (R10's best-measured config — FROZEN; R15 W-in-reg rewrite
// regressed and was reverted) ----
// Template VMODE: 0: 3-mult, write hi+lo (q). 2: 3-mult, write hi only (k).
//                 1: single-mult, write f16 transposed [hb,D,S] (v).
template <int VMODE>
__global__ __launch_bounds__(256, 2) void proj_kernel(
    const float* __restrict__ A,
    const _Float16* __restrict__ Whi, const _Float16* __restrict__ Wlo,
    const float* __restrict__ bias, float oscale, int h0,
    _Float16* __restrict__ Ohi, _Float16* __restrict__ Olo) {
  constexpr bool TMULT = (VMODE != 1);
  __shared__ _Float16 a_hi[128 * VSTRIDE] __attribute__((aligned(16)));
  __shared__ _Float16 b_hi[128 * VSTRIDE] __attribute__((aligned(16)));
  __shared__ _Float16 a_lo[TMULT ? 128 * VSTRIDE : 8] __attribute__((aligned(16)));
  __shared__ _Float16 b_lo[TMULT ? 128 * VSTRIDE : 8] __attribute__((aligned(16)));
  const int tid = threadIdx.x;
  const int w = tid >> 6, lane = tid & 63;
  const int quad = lane >> 4, l15 = lane & 15;
  const int hb = blockIdx.z, h = h0 + (hb >> 3), b = hb & 7;
  const int s0 = blockIdx.x * 128, d0 = blockIdx.y * 128;
  const int wr = w >> 1, wc = w & 1;
  const f32x4 fz = {0.f, 0.f, 0.f, 0.f};
  f32x4 acc[4][4];
#pragma unroll
  for (int i = 0; i < 4; ++i)
#pragma unroll
    for (int j = 0; j < 4; ++j) acc[i][j] = fz;
  const size_t arow0 = (size_t)b * S_ + s0;
  const size_t wrow0 = (size_t)h * 256 + d0;
  for (int kk = 0; kk < 8; ++kk) {
    const int f0 = kk * 32;
    __syncthreads();
#pragma unroll
    for (int i = 0; i < 2; ++i) {
      int cc = i * 256 + tid;
      int r = cc >> 2, ch = (cc & 3) * 8;
      half8 hv, lv;
      split8(A + (arow0 + r) * 256 + f0 + ch, hv, lv);
      *(half8*)&a_hi[r * VSTRIDE + ch] = hv;
      size_t woff = (wrow0 + r) * 256 + f0 + ch;
      *(half8*)&b_hi[r * VSTRIDE + ch] = *(const half8*)(Whi + woff);
      if (TMULT) {
        *(half8*)&a_lo[r * VSTRIDE + ch] = lv;
        *(half8*)&b_lo[r * VSTRIDE + ch] = *(const half8*)(Wlo + woff);
      }
    }
    __syncthreads();
    half8 afh[4], afl[4], bfh[4], bfl[4];
#pragma unroll
    for (int t = 0; t < 4; ++t) {
      int ar = wr * 64 + t * 16 + l15;
      afh[t] = *(const half8*)&a_hi[ar * VSTRIDE + quad * 8];
      int br = wc * 64 + t * 16 + l15;
      bfh[t] = *(const half8*)&b_hi[br * VSTRIDE + quad * 8];
      if (TMULT) {
        afl[t] = *(const half8*)&a_lo[ar * VSTRIDE + quad * 8];
        bfl[t] = *(const half8*)&b_lo[br * VSTRIDE + quad * 8];
      }
    }
#pragma unroll
    for (int rf = 0; rf < 4; ++rf)
#pragma unroll
      for (int cf = 0; cf < 4; ++cf) {
        acc[rf][cf] = __builtin_amdgcn_mfma_f32_16x16x32_f16(afh[rf], bfh[cf], acc[rf][cf], 0, 0, 0);
        if (TMULT) {
          acc[rf][cf] = __builtin_amdgcn_mfma_f32_16x16x32_f16(afh[rf], bfl[cf], acc[rf][cf], 0, 0, 0);
          acc[rf][cf] = __builtin_amdgcn_mfma_f32_16x16x32_f16(afl[rf], bfh[cf], acc[rf][cf], 0, 0, 0);
        }
      }
  }
  // epilogue: C/D layout row = quad*4+reg (s), col = lane&15 (d)
#pragma unroll
  for (int rf = 0; rf < 4; ++rf) {
#pragma unroll
    for (int cf = 0; cf < 4; ++cf) {
      const int d = d0 + wc * 64 + cf * 16 + l15;
      const float bv = bias[h * 256 + d];
      if (VMODE != 1) {
#pragma unroll
        for (int r = 0; r < 4; ++r) {
          const int s = s0 + wr * 64 + rf * 16 + quad * 4 + r;
          float val = (acc[rf][cf][r] + bv) * oscale;
          _Float16 hvv = (_Float16)val;
          size_t idx = ((size_t)hb * S_ + s) * 256 + d;
          Ohi[idx] = hvv;
          if (VMODE == 0) Olo[idx] = (_Float16)(val - (float)hvv);
        }
      } else {
        // lane holds 4 consecutive s for fixed d -> coalesced half4 store along S
        half4v pack;
#pragma unroll
        for (int r = 0; r < 4; ++r) pack[r] = (_Float16)((acc[rf][cf][r] + bv) * oscale);
        size_t idx = ((size_t)hb * 256 + d) * S_ + s0 + wr * 64 + rf * 16 + quad * 4;
        *(half4v*)(Ohi + idx) = pack;
      }
    }
  }
}

// ---------------- flash attention + fused C-projection — R18 ----------------
// Base = R1 (337us, VGPR 108, no spills). R16/R17 (32x32, 1-wave-32q) validated that
// sharing K/V LDS reads across more q-rows halves LDS+HBM traffic (conflicts 4.5e7
// -> 8.4e6) but died on a hard 256 arch-VGPR cap (-> 23MB spill writes). R18 gets the
// same sharing at 16x16: each wave owns 32 q-rows as TWO 16-row groups. K-frag and
// V-frag LDS reads are q-independent -> read once, feed both groups' MFMAs. Arch regs:
// Q-frags 128 + temps ~50 < 256 (o_acc in AGPRs as in R1). Staging, 3-barrier
// structure, P-through-LDS, swapped-QK softmax: byte-identical to R1.
// Numerics per q-row identical to R1.
__global__ __launch_bounds__(256, 1) void flash_kernel(
    const _Float16* __restrict__ qhi, const _Float16* __restrict__ qlo,
    const _Float16* __restrict__ khi,
    const _Float16* __restrict__ vt, const float* __restrict__ Cw,
    float* __restrict__ out, int h0) {
  __shared__ _Float16 khi_s[32 * KSTRIDE] __attribute__((aligned(16)));
  __shared__ _Float16 vt_s[256 * VSTRIDE] __attribute__((aligned(16)));
  __shared__ _Float16 p_s[4][2][16 * VSTRIDE] __attribute__((aligned(16)));
  const int tid = threadIdx.x, w = tid >> 6, lane = tid & 63;
  const int quad = lane >> 4, l15 = lane & 15;
  const int hb = blockIdx.y, h = h0 + (hb >> 3), b = hb & 7;
  const int qbase = blockIdx.x * 128 + w * 32;   // wave owns 32 q-rows: groups +0, +16
  // q fragments in registers (softmax scale 1/16 folded into q projection)
  half8 qfh[2][8], qfl[2][8];
#pragma unroll
  for (int g = 0; g < 2; ++g) {
    size_t qrow = (size_t)hb * S_ + qbase + g * 16 + l15;
    const _Float16* qh = qhi + qrow * 256 + quad * 8;
    const _Float16* ql = qlo + qrow * 256 + quad * 8;
#pragma unroll
    for (int ks = 0; ks < 8; ++ks) {
      qfh[g][ks] = *(const half8*)(qh + ks * 32);
      qfl[g][ks] = *(const half8*)(ql + ks * 32);
    }
  }
  const f32x4 fz = {0.f, 0.f, 0.f, 0.f};
  f32x4 o_acc[2][16];
#pragma unroll
  for (int g = 0; g < 2; ++g)
#pragma unroll
    for (int df = 0; df < 16; ++df) o_acc[g][df] = fz;
  float m_r[2], l_r[2];
#pragma unroll
  for (int g = 0; g < 2; ++g) { m_r[g] = -3.0e38f; l_r[g] = 0.f; }

  for (int kt = 0; kt < 64; ++kt) {
    __syncthreads();  // prior iteration's PV reads of k/v LDS are done
    {
      size_t kbase = ((size_t)hb * S_ + kt * 32) * 256;
#pragma unroll
      for (int i = 0; i < 4; ++i) {
        int cc = i * 256 + tid;
        int kr = cc >> 5, kch = (cc & 31) * 8;
        *(half8*)&khi_s[kr * KSTRIDE + kch] = *(const half8*)(khi + kbase + kr * 256 + kch);
        int vd = cc >> 2, vch = (cc & 3) * 8;
        size_t voff = ((size_t)hb * 256 + vd) * S_ + kt * 32 + vch;
        *(half8*)&vt_s[vd * VSTRIDE + vch] = *(const half8*)(vt + voff);
      }
    }
    __syncthreads();
    // QK^T swapped: A = K-frag (shared by both q-groups!), B = Q.
    // C/D: row = quad*4+r = k-col (tile adds 16), col = l15 = q-row.
    f32x4 sc0[2], sc1[2];
#pragma unroll
    for (int g = 0; g < 2; ++g) { sc0[g] = fz; sc1[g] = fz; }
#pragma unroll
    for (int ks = 0; ks < 8; ++ks) {
      half8 bh0 = *(const half8*)&khi_s[(0 * 16 + l15) * KSTRIDE + ks * 32 + quad * 8];
      half8 bh1 = *(const half8*)&khi_s[(1 * 16 + l15) * KSTRIDE + ks * 32 + quad * 8];
#pragma unroll
      for (int g = 0; g < 2; ++g) {
        sc0[g] = __builtin_amdgcn_mfma_f32_16x16x32_f16(bh0, qfh[g][ks], sc0[g], 0, 0, 0);
        sc0[g] = __builtin_amdgcn_mfma_f32_16x16x32_f16(bh0, qfl[g][ks], sc0[g], 0, 0, 0);
        sc1[g] = __builtin_amdgcn_mfma_f32_16x16x32_f16(bh1, qfh[g][ks], sc1[g], 0, 0, 0);
        sc1[g] = __builtin_amdgcn_mfma_f32_16x16x32_f16(bh1, qfl[g][ks], sc1[g], 0, 0, 0);
      }
    }
    // online softmax per group (lane owns q-row l15, replicated across quads)
    float al_g[2];
#pragma unroll
    for (int g = 0; g < 2; ++g) {
      float v = fmaxf(fmaxf(fmaxf(sc0[g][0], sc0[g][1]), fmaxf(sc0[g][2], sc0[g][3])),
                      fmaxf(fmaxf(sc1[g][0], sc1[g][1]), fmaxf(sc1[g][2], sc1[g][3])));
      v = fmaxf(v, __shfl_xor(v, 16));
      v = fmaxf(v, __shfl_xor(v, 32));
      const float mn = fmaxf(m_r[g], v);
      const float al = __expf(m_r[g] - mn);
      m_r[g] = mn;
      float p0[4], p1[4], s = 0.f;
#pragma unroll
      for (int r = 0; r < 4; ++r) {
        p0[r] = __expf(sc0[g][r] - mn);
        p1[r] = __expf(sc1[g][r] - mn);
        s += p0[r] + p1[r];
      }
      s += __shfl_xor(s, 16);
      s += __shfl_xor(s, 32);
      l_r[g] = l_r[g] * al + s;
      al_g[g] = al;
      // P -> LDS: p_s[q=l15][k=quad*4+r (+16 for tile1)], packed half2 stores
      _Float16* pb = &p_s[w][g][l15 * VSTRIDE + quad * 4];
      half2v w0 = {(_Float16)p0[0], (_Float16)p0[1]};
      half2v w1 = {(_Float16)p0[2], (_Float16)p0[3]};
      half2v w2 = {(_Float16)p1[0], (_Float16)p1[1]};
      half2v w3 = {(_Float16)p1[2], (_Float16)p1[3]};
      *(half2v*)(pb) = w0;
      *(half2v*)(pb + 2) = w1;
      *(half2v*)(pb + 16) = w2;
      *(half2v*)(pb + 18) = w3;
    }
    // rescale O accumulators: gather al for o-rows quad*4+r (held at lane l15==row)
#pragma unroll
    for (int g = 0; g < 2; ++g) {
      float al_r[4];
#pragma unroll
      for (int r = 0; r < 4; ++r) al_r[r] = __shfl(al_g[g], quad * 4 + r);
#pragma unroll
      for (int df = 0; df < 16; ++df)
#pragma unroll
        for (int r = 0; r < 4; ++r) o_acc[g][df][r] *= al_r[r];
    }
    __syncthreads();  // phase barrier: keeps softmax and PV LDS phases aligned
    // PV: P in A-layout from LDS, V^T as B operand (vf shared by both groups!)
    half8 pf0 = *(const half8*)&p_s[w][0][l15 * VSTRIDE + quad * 8];
    half8 pf1 = *(const half8*)&p_s[w][1][l15 * VSTRIDE + quad * 8];
#pragma unroll
    for (int df = 0; df < 16; ++df) {
      half8 vf = *(const half8*)&vt_s[(df * 16 + l15) * VSTRIDE + quad * 8];
      o_acc[0][df] = __builtin_amdgcn_mfma_f32_16x16x32_f16(pf0, vf, o_acc[0][df], 0, 0, 0);
      o_acc[1][df] = __builtin_amdgcn_mfma_f32_16x16x32_f16(pf1, vf, o_acc[1][df], 0, 0, 0);
    }
  }
  // epilogue per group: normalize + fused C-projection out[b,s,j] += sum_d o*Cw
#pragma unroll
  for (int g = 0; g < 2; ++g) {
    float rcl[4];
#pragma unroll
    for (int r = 0; r < 4; ++r) rcl[r] = 1.0f / __shfl(l_r[g], quad * 4 + r);
    float part[32];
#pragma unroll
    for (int i = 0; i < 32; ++i) part[i] = 0.f;
#pragma unroll
    for (int df = 0; df < 16; ++df) {
      const float4* cwv = (const float4*)(Cw + ((size_t)h * 256 + df * 16 + l15) * 8);
      float4 c0 = cwv[0], c1 = cwv[1];
#pragma unroll
      for (int r = 0; r < 4; ++r) {
        float ov = o_acc[g][df][r] * rcl[r];
        part[r * 8 + 0] += ov * c0.x;
        part[r * 8 + 1] += ov * c0.y;
        part[r * 8 + 2] += ov * c0.z;
        part[r * 8 + 3] += ov * c0.w;
        part[r * 8 + 4] += ov * c1.x;
        part[r * 8 + 5] += ov * c1.y;
        part[r * 8 + 6] += ov * c1.z;
        part[r * 8 + 7] += ov * c1.w;
      }
    }
#pragma unroll
    for (int i = 0; i < 32; ++i) {
      float v = part[i];
      v += __shfl_xor(v, 1);
      v += __shfl_xor(v, 2);
      v += __shfl_xor(v, 4);
      v += __shfl_xor(v, 8);
      part[i] = v;
    }
    if (l15 == 0) {
#pragma unroll
      for (int r = 0; r < 4; ++r) {
        int s = qbase + g * 16 + quad * 4 + r;
#pragma unroll
        for (int j = 0; j < 8; ++j)
          atomicAdd(&out[((size_t)b * S_ + s) * 8 + j], part[r * 8 + j]);
      }
    }
  }
}

extern "C" void kernel_launch(void* const* d_in, const int* in_sizes, int n_in,
                              void* d_out, int out_size, void* d_ws, size_t ws_size,
                              hipStream_t stream) {
  const float* x  = (const float*)d_in[0];
  const float* bo = (const float*)d_in[1];
  const float* Qw = (const float*)d_in[2];
  const float* Qb = (const float*)d_in[3];
  const float* Kw = (const float*)d_in[4];
  const float* Kb = (const float*)d_in[5];
  const float* Vw = (const float*)d_in[6];
  const float* Vb = (const float*)d_in[7];
  const float* Cw = (const float*)d_in[8];
  const float* Cb = (const float*)d_in[9];
  float* out = (float*)d_out;

  const size_t NW  = (size_t)H_ * 256 * 256;
  const size_t NHB = (size_t)B_ * S_ * 256;
  const size_t ALN = 256;
  auto pad = [](size_t b) { return (b + 255) & ~(size_t)255; };

  // pick largest head-chunk HC in {8,4,2,1} whose scratch fits ws_size
  int HC = 8;
  while (HC > 1) {
    size_t need = 6 * pad(NW * 2) + 4 * pad((size_t)HC * NHB * 2) + ALN;
    if (need <= ws_size) break;
    HC >>= 1;
  }

  char* base = (char*)d_ws;
  size_t off = 0;
  auto carve = [&](size_t nelem) -> _Float16* {
    _Float16* p = (_Float16*)(base + off);
    off += pad(nelem * 2);
    return p;
  };
  _Float16* qwt_hi = carve(NW); _Float16* qwt_lo = carve(NW);
  _Float16* kwt_hi = carve(NW); _Float16* kwt_lo = carve(NW);
  _Float16* vwt_hi = carve(NW); _Float16* vwt_lo = carve(NW);
  const size_t NC = (size_t)HC * NHB;
  _Float16* q_hi = carve(NC); _Float16* q_lo = carve(NC);
  _Float16* k_hi = carve(NC);
  _Float16* v_t  = carve(NC);

  dim3 wg(4, 4, 8);
  split_w_kernel<<<wg, 256, 0, stream>>>(Qw, qwt_hi, qwt_lo);
  split_w_kernel<<<wg, 256, 0, stream>>>(Kw, kwt_hi, kwt_lo);
  split_w_kernel<<<wg, 256, 0, stream>>>(Vw, vwt_hi, vwt_lo);
  out_init_kernel<<<(B_ * S_ * 8) / 256, 256, 0, stream>>>(out, Cb);

  for (int h0 = 0; h0 < H_; h0 += HC) {
    dim3 pg(16, 2, HC * 8);
    // q: fold softmax scale 1/sqrt(256)=1/16 into the projection output
    proj_kernel<0><<<pg, 256, 0, stream>>>(bo, qwt_hi, qwt_lo, Qb, 0.0625f, h0, q_hi, q_lo);
    proj_kernel<2><<<pg, 256, 0, stream>>>(x, kwt_hi, kwt_lo, Kb, 1.0f, h0, k_hi, nullptr);
    proj_kernel<1><<<pg, 256, 0, stream>>>(x, vwt_hi, vwt_lo, Vb, 1.0f, h0, v_t, nullptr);
    dim3 fg(16, HC * 8);
    flash_kernel<<<fg, 256, 0, stream>>>(q_hi, q_lo, k_hi, v_t, Cw, out, h0);
  }
}

// Round 6
// 836.963 us; speedup vs baseline: 1.7689x; 1.2619x over previous
//
#include <hip/hip_runtime.h>

#define H_ 8
#define B_ 8
#define S_ 2048
#define D_ 256

// padded LDS strides (halves): kill 8/16-way bank conflicts, keep 16B alignment
#define KSTRIDE 264   // k-tile rows: 528B = 4 banks offset/row
#define VSTRIDE 40    // 32-col tiles: 80B = 20 banks offset/row
#define QTSTRIDE 136  // q-transpose rows: 128 d + pad, 272B = 16B-aligned

typedef __attribute__((ext_vector_type(8))) _Float16 half8;
typedef __attribute__((ext_vector_type(4))) _Float16 half4v;
typedef __attribute__((ext_vector_type(2))) _Float16 half2v;
typedef __attribute__((ext_vector_type(4))) float f32x4;

// split 8 consecutive fp32 into fp16 hi + lo residual
__device__ inline void split8(const float* __restrict__ p, half8& hv, half8& lv) {
  float4 a = *(const float4*)p, b = *(const float4*)(p + 4);
  hv[0] = (_Float16)a.x; hv[1] = (_Float16)a.y; hv[2] = (_Float16)a.z; hv[3] = (_Float16)a.w;
  hv[4] = (_Float16)b.x; hv[5] = (_Float16)b.y; hv[6] = (_Float16)b.z; hv[7] = (_Float16)b.w;
  lv[0] = (_Float16)(a.x - (float)hv[0]); lv[1] = (_Float16)(a.y - (float)hv[1]);
  lv[2] = (_Float16)(a.z - (float)hv[2]); lv[3] = (_Float16)(a.w - (float)hv[3]);
  lv[4] = (_Float16)(b.x - (float)hv[4]); lv[5] = (_Float16)(b.y - (float)hv[5]);
  lv[6] = (_Float16)(b.z - (float)hv[6]); lv[7] = (_Float16)(b.w - (float)hv[7]);
}

// ------- transpose + split weights via LDS tile: W[h][f][d] -> Wt hi/lo [h][d][f] -------
__global__ void split_w_kernel(const float* __restrict__ W,
                               _Float16* __restrict__ thi, _Float16* __restrict__ tlo) {
  __shared__ float t[64][65];
  const int h = blockIdx.z, f0 = blockIdx.x * 64, d0 = blockIdx.y * 64;
  const int col = threadIdx.x & 63, rg = threadIdx.x >> 6;
#pragma unroll
  for (int it = 0; it < 16; ++it) {
    int f = rg * 16 + it;
    t[f][col] = W[((size_t)h * 256 + f0 + f) * 256 + d0 + col];
  }
  __syncthreads();
#pragma unroll
  for (int it = 0; it < 16; ++it) {
    int d = rg * 16 + it;
    float v = t[col][d];
    _Float16 hv = (_Float16)v;
    size_t idx = ((size_t)h * 256 + d0 + d) * 256 + f0 + col;
    thi[idx] = hv;
    tlo[idx] = (_Float16)(v - (float)hv);
  }
}

// ---------------- out = Cb broadcast ----------------
__global__ void out_init_kernel(float* __restrict__ out, const float* __restrict__ Cb) {
  int i = blockIdx.x * blockDim.x + threadIdx.x;
  if (i < B_ * S_ * 8) out[i] = Cb[i & 7];
}

// ---- projection GEMM (R10's best-measured config — FROZEN) ----
// Used for K (VMODE 2) and V (VMODE 1) only; q-proj is fused into flash (R19).
template <int VMODE>
__global__ __launch_bounds__(256, 2) void proj_kernel(
    const float* __restrict__ A,
    const _Float16* __restrict__ Whi, const _Float16* __restrict__ Wlo,
    const float* __restrict__ bias, float oscale, int h0,
    _Float16* __restrict__ Ohi, _Float16* __restrict__ Olo) {
  constexpr bool TMULT = (VMODE != 1);
  __shared__ _Float16 a_hi[128 * VSTRIDE] __attribute__((aligned(16)));
  __shared__ _Float16 b_hi[128 * VSTRIDE] __attribute__((aligned(16)));
  __shared__ _Float16 a_lo[TMULT ? 128 * VSTRIDE : 8] __attribute__((aligned(16)));
  __shared__ _Float16 b_lo[TMULT ? 128 * VSTRIDE : 8] __attribute__((aligned(16)));
  const int tid = threadIdx.x;
  const int w = tid >> 6, lane = tid & 63;
  const int quad = lane >> 4, l15 = lane & 15;
  const int hb = blockIdx.z, h = h0 + (hb >> 3), b = hb & 7;
  const int s0 = blockIdx.x * 128, d0 = blockIdx.y * 128;
  const int wr = w >> 1, wc = w & 1;
  const f32x4 fz = {0.f, 0.f, 0.f, 0.f};
  f32x4 acc[4][4];
#pragma unroll
  for (int i = 0; i < 4; ++i)
#pragma unroll
    for (int j = 0; j < 4; ++j) acc[i][j] = fz;
  const size_t arow0 = (size_t)b * S_ + s0;
  const size_t wrow0 = (size_t)h * 256 + d0;
  for (int kk = 0; kk < 8; ++kk) {
    const int f0 = kk * 32;
    __syncthreads();
#pragma unroll
    for (int i = 0; i < 2; ++i) {
      int cc = i * 256 + tid;
      int r = cc >> 2, ch = (cc & 3) * 8;
      half8 hv, lv;
      split8(A + (arow0 + r) * 256 + f0 + ch, hv, lv);
      *(half8*)&a_hi[r * VSTRIDE + ch] = hv;
      size_t woff = (wrow0 + r) * 256 + f0 + ch;
      *(half8*)&b_hi[r * VSTRIDE + ch] = *(const half8*)(Whi + woff);
      if (TMULT) {
        *(half8*)&a_lo[r * VSTRIDE + ch] = lv;
        *(half8*)&b_lo[r * VSTRIDE + ch] = *(const half8*)(Wlo + woff);
      }
    }
    __syncthreads();
    half8 afh[4], afl[4], bfh[4], bfl[4];
#pragma unroll
    for (int t = 0; t < 4; ++t) {
      int ar = wr * 64 + t * 16 + l15;
      afh[t] = *(const half8*)&a_hi[ar * VSTRIDE + quad * 8];
      int br = wc * 64 + t * 16 + l15;
      bfh[t] = *(const half8*)&b_hi[br * VSTRIDE + quad * 8];
      if (TMULT) {
        afl[t] = *(const half8*)&a_lo[ar * VSTRIDE + quad * 8];
        bfl[t] = *(const half8*)&b_lo[br * VSTRIDE + quad * 8];
      }
    }
#pragma unroll
    for (int rf = 0; rf < 4; ++rf)
#pragma unroll
      for (int cf = 0; cf < 4; ++cf) {
        acc[rf][cf] = __builtin_amdgcn_mfma_f32_16x16x32_f16(afh[rf], bfh[cf], acc[rf][cf], 0, 0, 0);
        if (TMULT) {
          acc[rf][cf] = __builtin_amdgcn_mfma_f32_16x16x32_f16(afh[rf], bfl[cf], acc[rf][cf], 0, 0, 0);
          acc[rf][cf] = __builtin_amdgcn_mfma_f32_16x16x32_f16(afl[rf], bfh[cf], acc[rf][cf], 0, 0, 0);
        }
      }
  }
  // epilogue: C/D layout row = quad*4+reg (s), col = lane&15 (d)
#pragma unroll
  for (int rf = 0; rf < 4; ++rf) {
#pragma unroll
    for (int cf = 0; cf < 4; ++cf) {
      const int d = d0 + wc * 64 + cf * 16 + l15;
      const float bv = bias[h * 256 + d];
      if (VMODE != 1) {
#pragma unroll
        for (int r = 0; r < 4; ++r) {
          const int s = s0 + wr * 64 + rf * 16 + quad * 4 + r;
          float val = (acc[rf][cf][r] + bv) * oscale;
          _Float16 hvv = (_Float16)val;
          size_t idx = ((size_t)hb * S_ + s) * 256 + d;
          Ohi[idx] = hvv;
          if (VMODE == 0) Olo[idx] = (_Float16)(val - (float)hvv);
        }
      } else {
        // lane holds 4 consecutive s for fixed d -> coalesced half4 store along S
        half4v pack;
#pragma unroll
        for (int r = 0; r < 4; ++r) pack[r] = (_Float16)((acc[rf][cf][r] + bv) * oscale);
        size_t idx = ((size_t)hb * 256 + d) * S_ + s0 + wr * 64 + rf * 16 + quad * 4;
        *(half4v*)(Ohi + idx) = pack;
      }
    }
  }
}

// ---------------- flash attention + fused Q-projection + fused C-projection ----------------
// R19: kt-loop is EXACTLY R1 (337us, VGPR 108+64AGPR, 2 blk/CU — R16/R18 showed losing
// 2 blk/CU costs ~20%). New: q-proj fused as a prologue — each block computes its own
// 64 q-rows (q is the only fusable projection: K/V are consumed by all 32 blocks/hb).
// Swapped mfma(W,bo) gives D[d][q=l15]; 3-mult order matches proj<0> exactly
// (w_hi*a_hi, a_hi*w_lo, a_lo*w_hi per 32-k slice, slices ascending) -> numerics
// identical to the old proj+global round-trip. One-time 4-phase LDS transpose lands
// the result in the same qfh/qfl registers the kt-loop always used.
// Deletes: proj<0> dispatch (~190us), 268MB HBM (q hi/lo write+read).
__global__ __launch_bounds__(256, 2) void flash_kernel(
    const float* __restrict__ bo,
    const _Float16* __restrict__ qwhi, const _Float16* __restrict__ qwlo,
    const float* __restrict__ qbias,
    const _Float16* __restrict__ khi,
    const _Float16* __restrict__ vt, const float* __restrict__ Cw,
    float* __restrict__ out, int h0) {
  __shared__ _Float16 khi_s[32 * KSTRIDE] __attribute__((aligned(16)));
  __shared__ _Float16 vt_s[256 * VSTRIDE] __attribute__((aligned(16)));
  __shared__ _Float16 p_s[4][16 * VSTRIDE] __attribute__((aligned(16)));
  __shared__ _Float16 wbuf[256 * VSTRIDE] __attribute__((aligned(16)));
  const int tid = threadIdx.x, w = tid >> 6, lane = tid & 63;
  const int quad = lane >> 4, l15 = lane & 15;
  const int hb = blockIdx.y, h = h0 + (hb >> 3), b = hb & 7;
  const int qbase = blockIdx.x * 64;
  _Float16* psf = &p_s[0][0];  // flat view, 2560 halves

  // ---- fused q projection: qacc[df] = (bo row) x (Qw^T), D[d][q=l15] ----
  const f32x4 fz = {0.f, 0.f, 0.f, 0.f};
  f32x4 qacc[16];
#pragma unroll
  for (int df = 0; df < 16; ++df) qacc[df] = fz;
  for (int kk = 0; kk < 8; ++kk) {
    __syncthreads();
    // stage Qw^T hi -> vt_s, lo -> wbuf: [256 d][32 f], 4 half8/thread each
#pragma unroll
    for (int i = 0; i < 4; ++i) {
      int c = i * 256 + tid;
      int dr = c >> 2, ch = (c & 3) * 8;
      size_t woff = ((size_t)h * 256 + dr) * 256 + kk * 32 + ch;
      *(half8*)&vt_s[dr * VSTRIDE + ch] = *(const half8*)(qwhi + woff);
      *(half8*)&wbuf[dr * VSTRIDE + ch] = *(const half8*)(qwlo + woff);
    }
    // stage bo hi -> khi_s, lo -> psf: [64 s][32 f], 1 split8/thread
    {
      int rrow = tid >> 2, ch = (tid & 3) * 8;
      half8 hv, lv;
      split8(bo + ((size_t)b * S_ + qbase + rrow) * 256 + kk * 32 + ch, hv, lv);
      *(half8*)&khi_s[rrow * VSTRIDE + ch] = hv;
      *(half8*)&psf[rrow * VSTRIDE + ch] = lv;
    }
    __syncthreads();
    half8 bh = *(const half8*)&khi_s[(w * 16 + l15) * VSTRIDE + quad * 8];
    half8 bl = *(const half8*)&psf[(w * 16 + l15) * VSTRIDE + quad * 8];
#pragma unroll
    for (int df = 0; df < 16; ++df) {
      half8 awh = *(const half8*)&vt_s[(df * 16 + l15) * VSTRIDE + quad * 8];
      half8 awl = *(const half8*)&wbuf[(df * 16 + l15) * VSTRIDE + quad * 8];
      // order matches proj<0>: a_hi*w_hi, a_hi*w_lo, a_lo*w_hi
      qacc[df] = __builtin_amdgcn_mfma_f32_16x16x32_f16(awh, bh, qacc[df], 0, 0, 0);
      qacc[df] = __builtin_amdgcn_mfma_f32_16x16x32_f16(awl, bh, qacc[df], 0, 0, 0);
      qacc[df] = __builtin_amdgcn_mfma_f32_16x16x32_f16(awh, bl, qacc[df], 0, 0, 0);
    }
  }
  // ---- bias + scale + hi/lo split + 4-phase LDS transpose into qfh/qfl ----
  // qacc layout: d = df*16 + quad*4 + r, q = l15. kt-loop needs q[row=l15][quad*8+ks*32].
  half8 qfh[8], qfl[8];
#pragma unroll
  for (int ph = 0; ph < 4; ++ph) {
    const bool lo = ph >= 2;
    const int dh = (ph & 1) * 8;  // which 128-d half
    __syncthreads();
#pragma unroll
    for (int dfi = 0; dfi < 8; ++dfi) {
      int df = dh + dfi;
#pragma unroll
      for (int rp = 0; rp < 2; ++rp) {
        half2v hw;
#pragma unroll
        for (int rr = 0; rr < 2; ++rr) {
          int r = rp * 2 + rr;
          float bv = qbias[h * 256 + df * 16 + quad * 4 + r];
          float val = (qacc[df][r] + bv) * 0.0625f;  // softmax 1/16 folded in
          _Float16 hv = (_Float16)val;
          hw[rr] = lo ? (_Float16)(val - (float)hv) : hv;
        }
        *(half2v*)&vt_s[(w * 16 + l15) * QTSTRIDE + dfi * 16 + quad * 4 + rp * 2] = hw;
      }
    }
    __syncthreads();
#pragma unroll
    for (int k2 = 0; k2 < 4; ++k2) {
      half8 v = *(const half8*)&vt_s[(w * 16 + l15) * QTSTRIDE + k2 * 32 + quad * 8];
      if (lo) qfl[(ph & 1) * 4 + k2] = v;
      else    qfh[(ph & 1) * 4 + k2] = v;
    }
  }

  // ---- kt-loop: byte-identical to R1 ----
  f32x4 o_acc[16];
#pragma unroll
  for (int df = 0; df < 16; ++df) o_acc[df] = fz;
  float m_r = -3.0e38f, l_r = 0.f;

  for (int kt = 0; kt < 64; ++kt) {
    __syncthreads();  // prior iteration's PV reads of k/v LDS are done
    {
      size_t kbase = ((size_t)hb * S_ + kt * 32) * 256;
#pragma unroll
      for (int i = 0; i < 4; ++i) {
        int cc = i * 256 + tid;
        int kr = cc >> 5, kch = (cc & 31) * 8;
        *(half8*)&khi_s[kr * KSTRIDE + kch] = *(const half8*)(khi + kbase + kr * 256 + kch);
        int vd = cc >> 2, vch = (cc & 3) * 8;
        size_t voff = ((size_t)hb * 256 + vd) * S_ + kt * 32 + vch;
        *(half8*)&vt_s[vd * VSTRIDE + vch] = *(const half8*)(vt + voff);
      }
    }
    __syncthreads();
    // QK^T swapped: A = K-frag, B = Q-frag. C: row = quad*4+r = k-col, col = l15 = q.
    f32x4 sc0 = fz, sc1 = fz;
#pragma unroll
    for (int ks = 0; ks < 8; ++ks) {
      half8 bh0 = *(const half8*)&khi_s[(0 * 16 + l15) * KSTRIDE + ks * 32 + quad * 8];
      sc0 = __builtin_amdgcn_mfma_f32_16x16x32_f16(bh0, qfh[ks], sc0, 0, 0, 0);
      sc0 = __builtin_amdgcn_mfma_f32_16x16x32_f16(bh0, qfl[ks], sc0, 0, 0, 0);
      half8 bh1 = *(const half8*)&khi_s[(1 * 16 + l15) * KSTRIDE + ks * 32 + quad * 8];
      sc1 = __builtin_amdgcn_mfma_f32_16x16x32_f16(bh1, qfh[ks], sc1, 0, 0, 0);
      sc1 = __builtin_amdgcn_mfma_f32_16x16x32_f16(bh1, qfl[ks], sc1, 0, 0, 0);
    }
    // online softmax, in-register: lane owns q-row l15; 2 cross-quad shfls.
    float v = fmaxf(fmaxf(fmaxf(sc0[0], sc0[1]), fmaxf(sc0[2], sc0[3])),
                    fmaxf(fmaxf(sc1[0], sc1[1]), fmaxf(sc1[2], sc1[3])));
    v = fmaxf(v, __shfl_xor(v, 16));
    v = fmaxf(v, __shfl_xor(v, 32));
    const float mn = fmaxf(m_r, v);
    const float al = __expf(m_r - mn);
    m_r = mn;
    float p0[4], p1[4], s = 0.f;
#pragma unroll
    for (int r = 0; r < 4; ++r) {
      p0[r] = __expf(sc0[r] - mn);
      p1[r] = __expf(sc1[r] - mn);
      s += p0[r] + p1[r];
    }
    s += __shfl_xor(s, 16);
    s += __shfl_xor(s, 32);
    l_r = l_r * al + s;
    // P -> LDS: p_s[q=l15][k=quad*4+r (+16 for tile1)], packed half2 stores
    {
      _Float16* pb = &p_s[w][l15 * VSTRIDE + quad * 4];
      half2v w0 = {(_Float16)p0[0], (_Float16)p0[1]};
      half2v w1 = {(_Float16)p0[2], (_Float16)p0[3]};
      half2v w2 = {(_Float16)p1[0], (_Float16)p1[1]};
      half2v w3 = {(_Float16)p1[2], (_Float16)p1[3]};
      *(half2v*)(pb) = w0;
      *(half2v*)(pb + 2) = w1;
      *(half2v*)(pb + 16) = w2;
      *(half2v*)(pb + 18) = w3;
    }
    // rescale O accumulator: gather al for o-rows quad*4+r (held at lane l15==row)
    float al_r[4];
#pragma unroll
    for (int r = 0; r < 4; ++r) al_r[r] = __shfl(al, quad * 4 + r);
#pragma unroll
    for (int df = 0; df < 16; ++df)
#pragma unroll
      for (int r = 0; r < 4; ++r) o_acc[df][r] *= al_r[r];
    __syncthreads();  // phase barrier: keeps softmax and PV LDS phases aligned
    // PV: P in A-layout from LDS, V^T as B operand
    half8 pf = *(const half8*)&p_s[w][l15 * VSTRIDE + quad * 8];
#pragma unroll
    for (int df = 0; df < 16; ++df) {
      half8 vf = *(const half8*)&vt_s[(df * 16 + l15) * VSTRIDE + quad * 8];
      o_acc[df] = __builtin_amdgcn_mfma_f32_16x16x32_f16(pf, vf, o_acc[df], 0, 0, 0);
    }
  }
  // epilogue: normalize + fused C-projection out[b,s,j] += sum_d o*Cw
  float rcl[4];
#pragma unroll
  for (int r = 0; r < 4; ++r) rcl[r] = 1.0f / __shfl(l_r, quad * 4 + r);
  float part[32];
#pragma unroll
  for (int i = 0; i < 32; ++i) part[i] = 0.f;
#pragma unroll
  for (int df = 0; df < 16; ++df) {
    const float4* cwv = (const float4*)(Cw + ((size_t)h * 256 + df * 16 + l15) * 8);
    float4 c0 = cwv[0], c1 = cwv[1];
#pragma unroll
    for (int r = 0; r < 4; ++r) {
      float ov = o_acc[df][r] * rcl[r];
      part[r * 8 + 0] += ov * c0.x;
      part[r * 8 + 1] += ov * c0.y;
      part[r * 8 + 2] += ov * c0.z;
      part[r * 8 + 3] += ov * c0.w;
      part[r * 8 + 4] += ov * c1.x;
      part[r * 8 + 5] += ov * c1.y;
      part[r * 8 + 6] += ov * c1.z;
      part[r * 8 + 7] += ov * c1.w;
    }
  }
#pragma unroll
  for (int i = 0; i < 32; ++i) {
    float v = part[i];
    v += __shfl_xor(v, 1);
    v += __shfl_xor(v, 2);
    v += __shfl_xor(v, 4);
    v += __shfl_xor(v, 8);
    part[i] = v;
  }
  if (l15 == 0) {
#pragma unroll
    for (int r = 0; r < 4; ++r) {
      int s = qbase + w * 16 + quad * 4 + r;
#pragma unroll
      for (int j = 0; j < 8; ++j)
        atomicAdd(&out[((size_t)b * S_ + s) * 8 + j], part[r * 8 + j]);
    }
  }
}

extern "C" void kernel_launch(void* const* d_in, const int* in_sizes, int n_in,
                              void* d_out, int out_size, void* d_ws, size_t ws_size,
                              hipStream_t stream) {
  const float* x  = (const float*)d_in[0];
  const float* bo = (const float*)d_in[1];
  const float* Qw = (const float*)d_in[2];
  const float* Qb = (const float*)d_in[3];
  const float* Kw = (const float*)d_in[4];
  const float* Kb = (const float*)d_in[5];
  const float* Vw = (const float*)d_in[6];
  const float* Vb = (const float*)d_in[7];
  const float* Cw = (const float*)d_in[8];
  const float* Cb = (const float*)d_in[9];
  float* out = (float*)d_out;

  const size_t NW  = (size_t)H_ * 256 * 256;
  const size_t NHB = (size_t)B_ * S_ * 256;
  const size_t ALN = 256;
  auto pad = [](size_t b) { return (b + 255) & ~(size_t)255; };

  // pick largest head-chunk HC in {8,4,2,1} whose scratch fits ws_size
  // (q hi/lo no longer materialized — only k_hi and v_t chunks)
  int HC = 8;
  while (HC > 1) {
    size_t need = 6 * pad(NW * 2) + 2 * pad((size_t)HC * NHB * 2) + ALN;
    if (need <= ws_size) break;
    HC >>= 1;
  }

  char* base = (char*)d_ws;
  size_t off = 0;
  auto carve = [&](size_t nelem) -> _Float16* {
    _Float16* p = (_Float16*)(base + off);
    off += pad(nelem * 2);
    return p;
  };
  _Float16* qwt_hi = carve(NW); _Float16* qwt_lo = carve(NW);
  _Float16* kwt_hi = carve(NW); _Float16* kwt_lo = carve(NW);
  _Float16* vwt_hi = carve(NW); _Float16* vwt_lo = carve(NW);
  const size_t NC = (size_t)HC * NHB;
  _Float16* k_hi = carve(NC);
  _Float16* v_t  = carve(NC);

  dim3 wg(4, 4, 8);
  split_w_kernel<<<wg, 256, 0, stream>>>(Qw, qwt_hi, qwt_lo);
  split_w_kernel<<<wg, 256, 0, stream>>>(Kw, kwt_hi, kwt_lo);
  split_w_kernel<<<wg, 256, 0, stream>>>(Vw, vwt_hi, vwt_lo);
  out_init_kernel<<<(B_ * S_ * 8) / 256, 256, 0, stream>>>(out, Cb);

  for (int h0 = 0; h0 < H_; h0 += HC) {
    dim3 pg(16, 2, HC * 8);
    proj_kernel<2><<<pg, 256, 0, stream>>>(x, kwt_hi, kwt_lo, Kb, 1.0f, h0, k_hi, nullptr);
    proj_kernel<1><<<pg, 256, 0, stream>>>(x, vwt_hi, vwt_lo, Vb, 1.0f, h0, v_t, nullptr);
    dim3 fg(32, HC * 8);
    flash_kernel<<<fg, 256, 0, stream>>>(bo, qwt_hi, qwt_lo, Qb, k_hi, v_t, Cw, out, h0);
  }
}